// Round 15
// baseline (41.419 us; speedup 1.0000x reference)
//
#include <hip/hip_runtime.h>

#define H 1024
#define W 1024
#define TILE 32
#define SR 40    // hsum rows: TILE + 8 (halo4)
#define SC 36    // hsum cols: TILE + 4
#define VR 36    // vw rows:   TILE + 4
#define VC 36    // vw cols:   TILE + 4

// LDS: s_su 40*36*8 = 11520 B + s_vw 36*36*16 = 20736 B -> 32256 B -> 5 blocks/CU.

__global__ __launch_bounds__(256)
void kuwahara_kernel(const float* __restrict__ inp, float* __restrict__ out) {
    __shared__ float2 s_su[SR][SC];   // (hsum luma, hsum luma^2), halo4 rows
    __shared__ float4 s_vw[VR][VC];   // (r, g, b, k->weight), edge-replicated

    const int tid = threadIdx.x;

    // ---- XCD-aware swizzle: each XCD owns 512 contiguous tiles (x-fastest) ----
    unsigned wg  = blockIdx.x;          // grid = 4096 linear blocks
    unsigned lin = (wg & 7u) * 512u + (wg >> 3);
    const int n  = lin >> 10;
    const int y0 = ((lin >> 5) & 31) * TILE;
    const int x0 = (lin & 31) * TILE;

    const float* __restrict__ pR = inp + ((size_t)(4*n + 0) << 20);
    const float* __restrict__ pG = inp + ((size_t)(4*n + 1) << 20);
    const float* __restrict__ pB = inp + ((size_t)(4*n + 2) << 20);
    const float* __restrict__ pK = inp + ((size_t)(4*n + 3) << 20);

    const int tx  = tid & 31;   // column within tile
    const int tg  = tid >> 5;   // row-group: owns rows 4*tg .. 4*tg+3
    const int gx  = x0 + tx;
    const int pr0 = tg << 2;

    // ---- k at this thread's 4 output pixels (fp32 exact; L1/L2-resident) ----
    float kc[4];
#pragma unroll
    for (int p = 0; p < 4; ++p)
        kc[p] = pK[((y0 + pr0 + p) << 10) + gx];

    // ---- stage 1: direct-load fused luma + horizontal 5-sums + s_vw fill.
    // 400 tasks: j in [0,40), q in [0,10). Each task loads its own 8-px rgb
    // span (2nd quad redundant with neighbor task -> L1/L2 hit under swizzle;
    // no shfl, no DS-pipe cross-lane traffic). q<9: hsum output; q==9: only
    // the s_vw fill for the last 2 halo cols.
    for (int idx = tid; idx < SR * 10; idx += 256) {
        int j = idx / 10, q = idx - j * 10;
        int gy  = y0 - 4 + j;
        int cy  = min(max(gy, 0), H - 1);
        int gcs = x0 - 4 + (q << 2);
        const int base = cy << 10;
        const bool hs    = (q < 9);
        const bool vwrow = (j >= 2) && (j < SR - 2);
        float rr[8], gg[8], bb[8], kk[4];
        if (gcs >= 0 && gcs <= W - 8) {          // x-interior: vector loads
            float4 ra = *(const float4*)(pR + base + gcs);
            float4 ga = *(const float4*)(pG + base + gcs);
            float4 ba = *(const float4*)(pB + base + gcs);
            rr[0]=ra.x; rr[1]=ra.y; rr[2]=ra.z; rr[3]=ra.w;
            gg[0]=ga.x; gg[1]=ga.y; gg[2]=ga.z; gg[3]=ga.w;
            bb[0]=ba.x; bb[1]=ba.y; bb[2]=ba.z; bb[3]=ba.w;
            if (hs) {
                float4 rb = *(const float4*)(pR + base + gcs + 4);
                float4 gb = *(const float4*)(pG + base + gcs + 4);
                float4 b2 = *(const float4*)(pB + base + gcs + 4);
                rr[4]=rb.x; rr[5]=rb.y; rr[6]=rb.z; rr[7]=rb.w;
                gg[4]=gb.x; gg[5]=gb.y; gg[6]=gb.z; gg[7]=gb.w;
                bb[4]=b2.x; bb[5]=b2.y; bb[6]=b2.z; bb[7]=b2.w;
            }
            if (vwrow) {
                float4 k4 = *(const float4*)(pK + base + gcs);
                kk[0]=k4.x; kk[1]=k4.y; kk[2]=k4.z; kk[3]=k4.w;
            }
        } else {                                  // x-border: clamped scalar
            int ne = hs ? 8 : 4;
            for (int e = 0; e < ne; ++e) {
                int cx = min(max(gcs + e, 0), W - 1);
                rr[e] = pR[base + cx]; gg[e] = pG[base + cx]; bb[e] = pB[base + cx];
            }
            if (vwrow)
#pragma unroll
                for (int e = 0; e < 4; ++e)
                    kk[e] = pK[base + min(max(gcs + e, 0), W - 1)];
        }
        bool rowIn = ((unsigned)gy < (unsigned)H);
        if (hs) {
            float l[8], m[8];
#pragma unroll
            for (int e = 0; e < 8; ++e) {
                bool colIn = ((unsigned)(gcs + e) < (unsigned)W);
                float lv = (rowIn && colIn)
                    ? fmaf(0.2126f, rr[e], fmaf(0.7152f, gg[e], 0.0722f * bb[e]))
                    : 0.0f;                       // zero pad rows AND cols
                l[e] = lv; m[e] = lv * lv;
            }
            float s0 = ((l[0] + l[1]) + (l[2] + l[3])) + l[4];
            float s1 = s0 - l[0] + l[5];
            float s2 = s1 - l[1] + l[6];
            float s3 = s2 - l[2] + l[7];
            float u0 = ((m[0] + m[1]) + (m[2] + m[3])) + m[4];
            float u1 = u0 - m[0] + m[5];
            float u2 = u1 - m[1] + m[6];
            float u3 = u2 - m[2] + m[7];
            int c = q << 2;
            *(float4*)&s_su[j][c]     = make_float4(s0, u0, s1, u1);
            *(float4*)&s_su[j][c + 2] = make_float4(s2, u2, s3, u3);
        }
        if (vwrow) {                // s_vw from SAME regs; rotated write order
#pragma unroll
            for (int e = 0; e < 4; ++e) {
                int er = (e + q) & 3;
                int iv = (q << 2) + er - 2;
                if ((unsigned)iv < (unsigned)VC)
                    s_vw[j - 2][iv] = make_float4(rr[er], gg[er], bb[er], kk[er]);
            }
        }
    }
    __syncthreads();

    // ---- stage 3: vertical 5-sum -> variance -> weight. 2-col x 4-row tasks,
    // sliding vertical sums: 8 b128 reads -> 8 weights. 162 tasks, single pass.
    if (tid < 162) {
        int j4r = tid / 18, q = tid - j4r * 18;
        int j4  = j4r << 2;                     // rows j4 .. j4+3
        int c   = q << 1;                       // cols c, c+1
        int g0  = x0 - 2 + c;
        bool okx = (g0 >= 0) && (g0 + 1 <= W - 1);
        bool oky = (y0 - 2 + j4 >= 0) && (y0 - 2 + j4 + 3 <= H - 1);
        if (okx && oky) {                       // fast: all 8 centers unclamped
            float4 r0 = *(const float4*)&s_su[j4 + 0][c];
            float4 r1 = *(const float4*)&s_su[j4 + 1][c];
            float4 r2 = *(const float4*)&s_su[j4 + 2][c];
            float4 r3 = *(const float4*)&s_su[j4 + 3][c];
            float4 r4 = *(const float4*)&s_su[j4 + 4][c];
            float4 r5 = *(const float4*)&s_su[j4 + 5][c];
            float4 r6 = *(const float4*)&s_su[j4 + 6][c];
            float4 r7 = *(const float4*)&s_su[j4 + 7][c];
            float sx = (((r0.x + r1.x) + (r2.x + r3.x)) + r4.x);
            float sy = (((r0.y + r1.y) + (r2.y + r3.y)) + r4.y);
            float sz = (((r0.z + r1.z) + (r2.z + r3.z)) + r4.z);
            float sw = (((r0.w + r1.w) + (r2.w + r3.w)) + r4.w);
#pragma unroll
            for (int jj = 0; jj < 4; ++jj) {
                {
                    float mean = sx * 0.04f, msq = sy * 0.04f;
                    float var  = fabsf(msq - mean * mean);
                    s_vw[j4 + jj][c].w = __expf(-var * 64.0f * s_vw[j4 + jj][c].w);
                }
                {
                    float mean = sz * 0.04f, msq = sw * 0.04f;
                    float var  = fabsf(msq - mean * mean);
                    s_vw[j4 + jj][c + 1].w = __expf(-var * 64.0f * s_vw[j4 + jj][c + 1].w);
                }
                if (jj < 3) {                   // slide window down one row
                    const float4 rl = (jj == 0) ? r0 : (jj == 1) ? r1 : r2;
                    const float4 rh = (jj == 0) ? r5 : (jj == 1) ? r6 : r7;
                    sx += rh.x - rl.x;  sy += rh.y - rl.y;
                    sz += rh.z - rl.z;  sw += rh.w - rl.w;
                }
            }
        } else {                                // border: per-output scalar
#pragma unroll
            for (int jj = 0; jj < 4; ++jj) {
                int j2 = j4 + jj;
                int gyc = min(max(y0 - 2 + j2, 0), H - 1);
                int js  = gyc - y0 + 2;
#pragma unroll
                for (int e = 0; e < 2; ++e) {
                    int is = min(max(g0 + e, 0), W - 1) - x0 + 2;
                    float ss = 0.f, sq = 0.f;
#pragma unroll
                    for (int r = 0; r < 5; ++r) {
                        float2 v = s_su[js + r][is];
                        ss += v.x; sq += v.y;
                    }
                    float mean = ss * 0.04f, msq = sq * 0.04f;
                    float var  = fabsf(msq - mean * mean);
                    s_vw[j2][c + e].w = __expf(-var * 64.0f * s_vw[j2][c + e].w);
                }
            }
        }
    }
    __syncthreads();

    // ---- spatial-falloff constants (late, short live ranges) ----
    float t1[4], t4[4];
#pragma unroll
    for (int p = 0; p < 4; ++p) {
        float t = __expf(-2.56f * (1.0f - kc[p]));   // t^(dx^2+dy^2) base
        t1[p] = t;
        t4[p] = (t * t) * (t * t);
    }

    // ---- stage 4: 25-tap filter; factorized row sums shared across 4 px ----
    float accR[4], accG[4], accB[4], accW[4];
    float ctrR[4], ctrG[4], ctrB[4];
#pragma unroll
    for (int p = 0; p < 4; ++p) { accR[p] = accG[p] = accB[p] = accW[p] = 0.f; }

#pragma unroll
    for (int r = 0; r < 8; ++r) {
        const float4* row = &s_vw[pr0 + r][tx];      // single base, imm offsets
        float4 a0 = row[0], a1 = row[1], a2 = row[2], a3 = row[3], a4 = row[4];
        // partial sums by |dx|: S0 (dx=0), S1 (|dx|=1), S2 (|dx|=2)
        float S0w = a2.w;
        float S0x = a2.w * a2.x, S0y = a2.w * a2.y, S0z = a2.w * a2.z;
        float S1w = a1.w + a3.w;
        float S1x = a1.w * a1.x + a3.w * a3.x;
        float S1y = a1.w * a1.y + a3.w * a3.y;
        float S1z = a1.w * a1.z + a3.w * a3.z;
        float S2w = a0.w + a4.w;
        float S2x = a0.w * a0.x + a4.w * a4.x;
        float S2y = a0.w * a0.y + a4.w * a4.y;
        float S2z = a0.w * a0.z + a4.w * a4.z;
#pragma unroll
        for (int p = 0; p < 4; ++p) {
            const int dy = r - 2 - p;                // compile-time after unroll
            if (dy < -2 || dy > 2) continue;
            const int ady = dy < 0 ? -dy : dy;
            float rw = S0w + t1[p] * S1w + t4[p] * S2w;
            float rx = S0x + t1[p] * S1x + t4[p] * S2x;
            float ry = S0y + t1[p] * S1y + t4[p] * S2y;
            float rz = S0z + t1[p] * S1z + t4[p] * S2z;
            if (ady == 0) {                          // center row: capture rgb
                ctrR[p] = a2.x; ctrG[p] = a2.y; ctrB[p] = a2.z;
                accR[p] += rx; accG[p] += ry; accB[p] += rz; accW[p] += rw;
            } else {
                float rf = (ady == 1) ? t1[p] : t4[p];
                accR[p] += rf * rx; accG[p] += rf * ry;
                accB[p] += rf * rz; accW[p] += rf * rw;
            }
        }
    }

    float* __restrict__ oR = out + ((size_t)(3*n + 0) << 20);
    float* __restrict__ oG = out + ((size_t)(3*n + 1) << 20);
    float* __restrict__ oB = out + ((size_t)(3*n + 2) << 20);
#pragma unroll
    for (int p = 0; p < 4; ++p) {
        float cb = 16.0f + kc[p] * (0.001f - 16.0f); // center boost
        accR[p] += cb * ctrR[p];
        accG[p] += cb * ctrG[p];
        accB[p] += cb * ctrB[p];
        accW[p] += cb;
        float inv = __builtin_amdgcn_rcpf(accW[p]);
        int off = ((y0 + pr0 + p) << 10) + gx;
        oR[off] = ctrR[p] + kc[p] * (accR[p] * inv - ctrR[p]);
        oG[off] = ctrG[p] + kc[p] * (accG[p] * inv - ctrG[p]);
        oB[off] = ctrB[p] + kc[p] * (accB[p] * inv - ctrB[p]);
    }
}

extern "C" void kernel_launch(void* const* d_in, const int* in_sizes, int n_in,
                              void* d_out, int out_size, void* d_ws, size_t ws_size,
                              hipStream_t stream) {
    const float* inp = (const float*)d_in[0];
    float* out = (float*)d_out;
    hipLaunchKernelGGL(kuwahara_kernel, dim3(4096), dim3(256), 0, stream, inp, out);
}

// Round 16
// 38.346 us; speedup vs baseline: 1.0801x; 1.0801x over previous
//
#include <hip/hip_runtime.h>

#define H 1024
#define W 1024
#define TILE 32
#define SR 40    // hsum rows: TILE + 8 (halo4)
#define SC 36    // hsum cols: TILE + 4
#define VR 36    // vw rows:   TILE + 4
#define VC 36    // vw cols:   TILE + 4

// LDS: s_su 40*36*8 = 11520 B + s_vw 36*36*16 = 20736 B -> 32256 B -> 5 blocks/CU.

__global__ __launch_bounds__(256)
void kuwahara_kernel(const float* __restrict__ inp, float* __restrict__ out) {
    __shared__ float2 s_su[SR][SC];   // (hsum luma, hsum luma^2), halo4 rows
    __shared__ float4 s_vw[VR][VC];   // (r, g, b, k->weight), edge-replicated

    const int tid = threadIdx.x;

    // ---- XCD-aware swizzle: each XCD owns 512 contiguous tiles (x-fastest) ----
    unsigned wg  = blockIdx.x;          // grid = 4096 linear blocks
    unsigned lin = (wg & 7u) * 512u + (wg >> 3);
    const int n  = lin >> 10;
    const int y0 = ((lin >> 5) & 31) * TILE;
    const int x0 = (lin & 31) * TILE;

    const float* __restrict__ pR = inp + ((size_t)(4*n + 0) << 20);
    const float* __restrict__ pG = inp + ((size_t)(4*n + 1) << 20);
    const float* __restrict__ pB = inp + ((size_t)(4*n + 2) << 20);
    const float* __restrict__ pK = inp + ((size_t)(4*n + 3) << 20);

    const int tx  = tid & 31;   // column within tile
    const int tg  = tid >> 5;   // row-group: owns rows 4*tg .. 4*tg+3
    const int gx  = x0 + tx;
    const int pr0 = tg << 2;

    // ---- k at this thread's 4 output pixels (fp32 exact; L1/L2-resident) ----
    float kc[4];
#pragma unroll
    for (int p = 0; p < 4; ++p)
        kc[p] = pK[((y0 + pr0 + p) << 10) + gx];

    // ---- stage 1: fused luma + horizontal 5-sums + s_vw fill (shfl_down),
    // SOFTWARE-PIPELINED: load BOTH passes' rgbk into registers first (global
    // loads don't alias LDS, so they issue back-to-back and one vmcnt drain
    // covers both), then process+write. 10 lanes/row; 6 rows/wave; 2 passes.
    {
        const int lane = tid & 63;
        const int wid  = tid >> 6;
        const int rloc = lane / 10;            // 0..5 active, 6 idle
        const int qq   = lane - rloc * 10;     // quad index 0..9
        const int gcs  = x0 - 4 + (qq << 2);

        float rr[2][4], gg[2][4], bb[2][4], kk[2][4];
        bool  actv[2], vwv[2];
        int   rowv[2];

        // ---- load phase: both passes ----
#pragma unroll
        for (int pass = 0; pass < 2; ++pass) {
            int row = pass * 24 + wid * 6 + rloc;
            rowv[pass] = row;
            bool act   = (rloc < 6) && (row < SR);
            actv[pass] = act;
            bool vwrow = act && (row >= 2) && (row < SR - 2);
            vwv[pass]  = vwrow;
#pragma unroll
            for (int e = 0; e < 4; ++e) {
                rr[pass][e] = 0.f; gg[pass][e] = 0.f;
                bb[pass][e] = 0.f; kk[pass][e] = 0.f;
            }
            if (act) {
                int gy = y0 - 4 + row;
                int cy = min(max(gy, 0), H - 1);
                const int base = cy << 10;
                if (gcs >= 0 && gcs <= W - 4) {         // x-interior: vector
                    float4 r4 = *(const float4*)(pR + base + gcs);
                    float4 g4 = *(const float4*)(pG + base + gcs);
                    float4 b4 = *(const float4*)(pB + base + gcs);
                    rr[pass][0]=r4.x; rr[pass][1]=r4.y; rr[pass][2]=r4.z; rr[pass][3]=r4.w;
                    gg[pass][0]=g4.x; gg[pass][1]=g4.y; gg[pass][2]=g4.z; gg[pass][3]=g4.w;
                    bb[pass][0]=b4.x; bb[pass][1]=b4.y; bb[pass][2]=b4.z; bb[pass][3]=b4.w;
                    if (vwrow) {
                        float4 k4 = *(const float4*)(pK + base + gcs);
                        kk[pass][0]=k4.x; kk[pass][1]=k4.y; kk[pass][2]=k4.z; kk[pass][3]=k4.w;
                    }
                } else {                                 // x-border: clamped
#pragma unroll
                    for (int e = 0; e < 4; ++e) {
                        int cx = min(max(gcs + e, 0), W - 1);
                        rr[pass][e] = pR[base + cx];
                        gg[pass][e] = pG[base + cx];
                        bb[pass][e] = pB[base + cx];
                        if (vwrow) kk[pass][e] = pK[base + cx];
                    }
                }
            }
        }

        // ---- process phase: luma, shfl, LDS writes ----
#pragma unroll
        for (int pass = 0; pass < 2; ++pass) {
            const int row = rowv[pass];
            const bool act = actv[pass];
            int gy = y0 - 4 + row;
            bool rowIn = ((unsigned)gy < (unsigned)H);
            float l0 = 0.f, l1 = 0.f, l2 = 0.f, l3 = 0.f;
            if (act) {
                float lv[4];
#pragma unroll
                for (int e = 0; e < 4; ++e) {
                    bool colIn = ((unsigned)(gcs + e) < (unsigned)W);
                    lv[e] = (rowIn && colIn)
                        ? fmaf(0.2126f, rr[pass][e],
                               fmaf(0.7152f, gg[pass][e], 0.0722f * bb[pass][e]))
                        : 0.0f;                          // zero pad rows AND cols
                }
                l0 = lv[0]; l1 = lv[1]; l2 = lv[2]; l3 = lv[3];
            }
            // neighbor quad's luma (same row: qq<=8 pulls from qq+1)
            float l4 = __shfl_down(l0, 1, 64);
            float l5 = __shfl_down(l1, 1, 64);
            float l6 = __shfl_down(l2, 1, 64);
            float l7 = __shfl_down(l3, 1, 64);
            if (act && qq < 9) {
                float s0 = ((l0 + l1) + (l2 + l3)) + l4;
                float s1 = s0 - l0 + l5;
                float s2 = s1 - l1 + l6;
                float s3 = s2 - l2 + l7;
                float m0=l0*l0, m1=l1*l1, m2=l2*l2, m3=l3*l3;
                float m4=l4*l4, m5=l5*l5, m6=l6*l6, m7=l7*l7;
                float u0 = ((m0 + m1) + (m2 + m3)) + m4;
                float u1 = u0 - m0 + m5;
                float u2 = u1 - m1 + m6;
                float u3 = u2 - m2 + m7;
                int c = qq << 2;
                *(float4*)&s_su[row][c]     = make_float4(s0, u0, s1, u1);
                *(float4*)&s_su[row][c + 2] = make_float4(s2, u2, s3, u3);
            }
            if (vwv[pass]) {            // s_vw from SAME regs; rotated write
#pragma unroll                          // order spreads the 16-bank qq stride
                for (int e = 0; e < 4; ++e) {
                    int er = (e + qq) & 3;
                    int iv = (qq << 2) + er - 2;
                    if ((unsigned)iv < (unsigned)VC)
                        s_vw[row - 2][iv] = make_float4(rr[pass][er], gg[pass][er],
                                                        bb[pass][er], kk[pass][er]);
                }
            }
        }
    }
    __syncthreads();

    // ---- stage 3: vertical 5-sum -> variance -> weight. 2-col x 4-row tasks,
    // sliding vertical sums: 8 b128 reads -> 8 weights. 162 tasks, single pass.
    if (tid < 162) {
        int j4r = tid / 18, q = tid - j4r * 18;
        int j4  = j4r << 2;                     // rows j4 .. j4+3
        int c   = q << 1;                       // cols c, c+1
        int g0  = x0 - 2 + c;
        bool okx = (g0 >= 0) && (g0 + 1 <= W - 1);
        bool oky = (y0 - 2 + j4 >= 0) && (y0 - 2 + j4 + 3 <= H - 1);
        if (okx && oky) {                       // fast: all 8 centers unclamped
            float4 r0 = *(const float4*)&s_su[j4 + 0][c];
            float4 r1 = *(const float4*)&s_su[j4 + 1][c];
            float4 r2 = *(const float4*)&s_su[j4 + 2][c];
            float4 r3 = *(const float4*)&s_su[j4 + 3][c];
            float4 r4 = *(const float4*)&s_su[j4 + 4][c];
            float4 r5 = *(const float4*)&s_su[j4 + 5][c];
            float4 r6 = *(const float4*)&s_su[j4 + 6][c];
            float4 r7 = *(const float4*)&s_su[j4 + 7][c];
            float sx = (((r0.x + r1.x) + (r2.x + r3.x)) + r4.x);
            float sy = (((r0.y + r1.y) + (r2.y + r3.y)) + r4.y);
            float sz = (((r0.z + r1.z) + (r2.z + r3.z)) + r4.z);
            float sw = (((r0.w + r1.w) + (r2.w + r3.w)) + r4.w);
#pragma unroll
            for (int jj = 0; jj < 4; ++jj) {
                {
                    float mean = sx * 0.04f, msq = sy * 0.04f;
                    float var  = fabsf(msq - mean * mean);
                    s_vw[j4 + jj][c].w = __expf(-var * 64.0f * s_vw[j4 + jj][c].w);
                }
                {
                    float mean = sz * 0.04f, msq = sw * 0.04f;
                    float var  = fabsf(msq - mean * mean);
                    s_vw[j4 + jj][c + 1].w = __expf(-var * 64.0f * s_vw[j4 + jj][c + 1].w);
                }
                if (jj < 3) {                   // slide window down one row
                    const float4 rl = (jj == 0) ? r0 : (jj == 1) ? r1 : r2;
                    const float4 rh = (jj == 0) ? r5 : (jj == 1) ? r6 : r7;
                    sx += rh.x - rl.x;  sy += rh.y - rl.y;
                    sz += rh.z - rl.z;  sw += rh.w - rl.w;
                }
            }
        } else {                                // border: per-output scalar
#pragma unroll
            for (int jj = 0; jj < 4; ++jj) {
                int j2 = j4 + jj;
                int gyc = min(max(y0 - 2 + j2, 0), H - 1);
                int js  = gyc - y0 + 2;
#pragma unroll
                for (int e = 0; e < 2; ++e) {
                    int is = min(max(g0 + e, 0), W - 1) - x0 + 2;
                    float ss = 0.f, sq = 0.f;
#pragma unroll
                    for (int r = 0; r < 5; ++r) {
                        float2 v = s_su[js + r][is];
                        ss += v.x; sq += v.y;
                    }
                    float mean = ss * 0.04f, msq = sq * 0.04f;
                    float var  = fabsf(msq - mean * mean);
                    s_vw[j2][c + e].w = __expf(-var * 64.0f * s_vw[j2][c + e].w);
                }
            }
        }
    }
    __syncthreads();

    // ---- spatial-falloff constants (late, short live ranges) ----
    float t1[4], t4[4];
#pragma unroll
    for (int p = 0; p < 4; ++p) {
        float t = __expf(-2.56f * (1.0f - kc[p]));   // t^(dx^2+dy^2) base
        t1[p] = t;
        t4[p] = (t * t) * (t * t);
    }

    // ---- stage 4: 25-tap filter; factorized row sums shared across 4 px ----
    float accR[4], accG[4], accB[4], accW[4];
    float ctrR[4], ctrG[4], ctrB[4];
#pragma unroll
    for (int p = 0; p < 4; ++p) { accR[p] = accG[p] = accB[p] = accW[p] = 0.f; }

#pragma unroll
    for (int r = 0; r < 8; ++r) {
        const float4* row = &s_vw[pr0 + r][tx];      // single base, imm offsets
        float4 a0 = row[0], a1 = row[1], a2 = row[2], a3 = row[3], a4 = row[4];
        // partial sums by |dx|: S0 (dx=0), S1 (|dx|=1), S2 (|dx|=2)
        float S0w = a2.w;
        float S0x = a2.w * a2.x, S0y = a2.w * a2.y, S0z = a2.w * a2.z;
        float S1w = a1.w + a3.w;
        float S1x = a1.w * a1.x + a3.w * a3.x;
        float S1y = a1.w * a1.y + a3.w * a3.y;
        float S1z = a1.w * a1.z + a3.w * a3.z;
        float S2w = a0.w + a4.w;
        float S2x = a0.w * a0.x + a4.w * a4.x;
        float S2y = a0.w * a0.y + a4.w * a4.y;
        float S2z = a0.w * a0.z + a4.w * a4.z;
#pragma unroll
        for (int p = 0; p < 4; ++p) {
            const int dy = r - 2 - p;                // compile-time after unroll
            if (dy < -2 || dy > 2) continue;
            const int ady = dy < 0 ? -dy : dy;
            float rw = S0w + t1[p] * S1w + t4[p] * S2w;
            float rx = S0x + t1[p] * S1x + t4[p] * S2x;
            float ry = S0y + t1[p] * S1y + t4[p] * S2y;
            float rz = S0z + t1[p] * S1z + t4[p] * S2z;
            if (ady == 0) {                          // center row: capture rgb
                ctrR[p] = a2.x; ctrG[p] = a2.y; ctrB[p] = a2.z;
                accR[p] += rx; accG[p] += ry; accB[p] += rz; accW[p] += rw;
            } else {
                float rf = (ady == 1) ? t1[p] : t4[p];
                accR[p] += rf * rx; accG[p] += rf * ry;
                accB[p] += rf * rz; accW[p] += rf * rw;
            }
        }
    }

    float* __restrict__ oR = out + ((size_t)(3*n + 0) << 20);
    float* __restrict__ oG = out + ((size_t)(3*n + 1) << 20);
    float* __restrict__ oB = out + ((size_t)(3*n + 2) << 20);
#pragma unroll
    for (int p = 0; p < 4; ++p) {
        float cb = 16.0f + kc[p] * (0.001f - 16.0f); // center boost
        accR[p] += cb * ctrR[p];
        accG[p] += cb * ctrG[p];
        accB[p] += cb * ctrB[p];
        accW[p] += cb;
        float inv = __builtin_amdgcn_rcpf(accW[p]);
        int off = ((y0 + pr0 + p) << 10) + gx;
        oR[off] = ctrR[p] + kc[p] * (accR[p] * inv - ctrR[p]);
        oG[off] = ctrG[p] + kc[p] * (accG[p] * inv - ctrG[p]);
        oB[off] = ctrB[p] + kc[p] * (accB[p] * inv - ctrB[p]);
    }
}

extern "C" void kernel_launch(void* const* d_in, const int* in_sizes, int n_in,
                              void* d_out, int out_size, void* d_ws, size_t ws_size,
                              hipStream_t stream) {
    const float* inp = (const float*)d_in[0];
    float* out = (float*)d_out;
    hipLaunchKernelGGL(kuwahara_kernel, dim3(4096), dim3(256), 0, stream, inp, out);
}

// Round 17
// 36.201 us; speedup vs baseline: 1.1441x; 1.0593x over previous
//
#include <hip/hip_runtime.h>

#define H 1024
#define W 1024
#define TILE 32
#define SR 40    // hsum rows: TILE + 8 (halo4)
#define SC 36    // hsum cols: TILE + 4
#define VR 36    // vw rows:   TILE + 4
#define VC 36    // vw cols:   TILE + 4

// LDS: s_su 40*36*8 = 11520 B + s_vw 36*36*16 = 20736 B -> 32256 B -> 5 blocks/CU.

__global__ __launch_bounds__(256)
void kuwahara_kernel(const float* __restrict__ inp, float* __restrict__ out) {
    __shared__ float2 s_su[SR][SC];   // (hsum luma, hsum luma^2), halo4 rows
    __shared__ float4 s_vw[VR][VC];   // (r, g, b, k->weight), edge-replicated

    const int tid = threadIdx.x;

    // ---- XCD-aware swizzle: each XCD owns 512 contiguous tiles (x-fastest) ----
    unsigned wg  = blockIdx.x;          // grid = 4096 linear blocks
    unsigned lin = (wg & 7u) * 512u + (wg >> 3);
    const int n  = lin >> 10;
    const int y0 = ((lin >> 5) & 31) * TILE;
    const int x0 = (lin & 31) * TILE;

    const float* __restrict__ pR = inp + ((size_t)(4*n + 0) << 20);
    const float* __restrict__ pG = inp + ((size_t)(4*n + 1) << 20);
    const float* __restrict__ pB = inp + ((size_t)(4*n + 2) << 20);
    const float* __restrict__ pK = inp + ((size_t)(4*n + 3) << 20);

    const int tx  = tid & 31;   // column within tile
    const int tg  = tid >> 5;   // row-group: owns rows 4*tg .. 4*tg+3
    const int gx  = x0 + tx;
    const int pr0 = tg << 2;

    // ---- k at this thread's 4 output pixels (fp32 exact; L1/L2-resident) ----
    float kc[4];
#pragma unroll
    for (int p = 0; p < 4; ++p)
        kc[p] = pK[((y0 + pr0 + p) << 10) + gx];

    // ---- stage 1 (fully fused, SINGLE load of rgbk per halo pixel):
    // luma + horizontal 5-sums via __shfl_down, AND s_vw fill from the same
    // registers. 10 lanes/row (one 4-px quad each); 6 rows/wave; 2 passes.
    {
        const int lane = tid & 63;
        const int wid  = tid >> 6;
        const int rloc = lane / 10;            // 0..5 active, 6 idle
        const int qq   = lane - rloc * 10;     // quad index 0..9
        const int gcs  = x0 - 4 + (qq << 2);
#pragma unroll
        for (int pass = 0; pass < 2; ++pass) {
            int row = pass * 24 + wid * 6 + rloc;
            bool act = (rloc < 6) && (row < SR);
            bool vwrow = act && (row >= 2) && (row < SR - 2);
            float l0 = 0.f, l1 = 0.f, l2 = 0.f, l3 = 0.f;
            float rr[4], gg[4], bb[4], kk[4];
            if (act) {
                int gy = y0 - 4 + row;
                int cy = min(max(gy, 0), H - 1);
                const int base = cy << 10;
                if (gcs >= 0 && gcs <= W - 4) {         // x-interior: vector
                    float4 r4 = *(const float4*)(pR + base + gcs);
                    float4 g4 = *(const float4*)(pG + base + gcs);
                    float4 b4 = *(const float4*)(pB + base + gcs);
                    rr[0]=r4.x; rr[1]=r4.y; rr[2]=r4.z; rr[3]=r4.w;
                    gg[0]=g4.x; gg[1]=g4.y; gg[2]=g4.z; gg[3]=g4.w;
                    bb[0]=b4.x; bb[1]=b4.y; bb[2]=b4.z; bb[3]=b4.w;
                    if (vwrow) {
                        float4 k4 = *(const float4*)(pK + base + gcs);
                        kk[0]=k4.x; kk[1]=k4.y; kk[2]=k4.z; kk[3]=k4.w;
                    }
                } else {                                 // x-border: clamped
#pragma unroll
                    for (int e = 0; e < 4; ++e) {
                        int cx = min(max(gcs + e, 0), W - 1);
                        rr[e] = pR[base + cx]; gg[e] = pG[base + cx];
                        bb[e] = pB[base + cx];
                        kk[e] = vwrow ? pK[base + cx] : 0.f;
                    }
                }
                bool rowIn = ((unsigned)gy < (unsigned)H);
                float lv[4];
#pragma unroll
                for (int e = 0; e < 4; ++e) {
                    bool colIn = ((unsigned)(gcs + e) < (unsigned)W);
                    lv[e] = (rowIn && colIn)
                        ? fmaf(0.2126f, rr[e], fmaf(0.7152f, gg[e], 0.0722f * bb[e]))
                        : 0.0f;                          // zero pad rows AND cols
                }
                l0 = lv[0]; l1 = lv[1]; l2 = lv[2]; l3 = lv[3];
            }
            // neighbor quad's luma (same row: qq<=8 pulls from qq+1)
            float l4 = __shfl_down(l0, 1, 64);
            float l5 = __shfl_down(l1, 1, 64);
            float l6 = __shfl_down(l2, 1, 64);
            float l7 = __shfl_down(l3, 1, 64);
            if (act && qq < 9) {
                float s0 = ((l0 + l1) + (l2 + l3)) + l4;
                float s1 = s0 - l0 + l5;
                float s2 = s1 - l1 + l6;
                float s3 = s2 - l2 + l7;
                float m0=l0*l0, m1=l1*l1, m2=l2*l2, m3=l3*l3;
                float m4=l4*l4, m5=l5*l5, m6=l6*l6, m7=l7*l7;
                float u0 = ((m0 + m1) + (m2 + m3)) + m4;
                float u1 = u0 - m0 + m5;
                float u2 = u1 - m1 + m6;
                float u3 = u2 - m2 + m7;
                int c = qq << 2;
                *(float4*)&s_su[row][c]     = make_float4(s0, u0, s1, u1);
                *(float4*)&s_su[row][c + 2] = make_float4(s2, u2, s3, u3);
            }
            if (vwrow) {                // s_vw from SAME regs; rotated write
#pragma unroll                          // order spreads the 16-bank qq stride
                for (int e = 0; e < 4; ++e) {
                    int er = (e + qq) & 3;
                    int iv = (qq << 2) + er - 2;
                    if ((unsigned)iv < (unsigned)VC)
                        s_vw[row - 2][iv] = make_float4(rr[er], gg[er], bb[er], kk[er]);
                }
            }
        }
    }
    __syncthreads();

    // ---- spatial-falloff constants: HOISTED before stage 3 so the 94 lanes
    // idle during stage 3 (tid >= 162) do their transcendentals in that
    // window instead of serializing after barrier 2. Depends only on kc.
    float t1[4], t4[4];
#pragma unroll
    for (int p = 0; p < 4; ++p) {
        float t = __expf(-2.56f * (1.0f - kc[p]));   // t^(dx^2+dy^2) base
        t1[p] = t;
        t4[p] = (t * t) * (t * t);
    }

    // ---- stage 3: vertical 5-sum -> variance -> weight. 2-col x 4-row tasks,
    // sliding vertical sums: 8 b128 reads -> 8 weights. 162 tasks, single pass.
    if (tid < 162) {
        int j4r = tid / 18, q = tid - j4r * 18;
        int j4  = j4r << 2;                     // rows j4 .. j4+3
        int c   = q << 1;                       // cols c, c+1
        int g0  = x0 - 2 + c;
        bool okx = (g0 >= 0) && (g0 + 1 <= W - 1);
        bool oky = (y0 - 2 + j4 >= 0) && (y0 - 2 + j4 + 3 <= H - 1);
        if (okx && oky) {                       // fast: all 8 centers unclamped
            float4 r0 = *(const float4*)&s_su[j4 + 0][c];
            float4 r1 = *(const float4*)&s_su[j4 + 1][c];
            float4 r2 = *(const float4*)&s_su[j4 + 2][c];
            float4 r3 = *(const float4*)&s_su[j4 + 3][c];
            float4 r4 = *(const float4*)&s_su[j4 + 4][c];
            float4 r5 = *(const float4*)&s_su[j4 + 5][c];
            float4 r6 = *(const float4*)&s_su[j4 + 6][c];
            float4 r7 = *(const float4*)&s_su[j4 + 7][c];
            float sx = (((r0.x + r1.x) + (r2.x + r3.x)) + r4.x);
            float sy = (((r0.y + r1.y) + (r2.y + r3.y)) + r4.y);
            float sz = (((r0.z + r1.z) + (r2.z + r3.z)) + r4.z);
            float sw = (((r0.w + r1.w) + (r2.w + r3.w)) + r4.w);
#pragma unroll
            for (int jj = 0; jj < 4; ++jj) {
                {
                    float mean = sx * 0.04f, msq = sy * 0.04f;
                    float var  = fabsf(msq - mean * mean);
                    s_vw[j4 + jj][c].w = __expf(-var * 64.0f * s_vw[j4 + jj][c].w);
                }
                {
                    float mean = sz * 0.04f, msq = sw * 0.04f;
                    float var  = fabsf(msq - mean * mean);
                    s_vw[j4 + jj][c + 1].w = __expf(-var * 64.0f * s_vw[j4 + jj][c + 1].w);
                }
                if (jj < 3) {                   // slide window down one row
                    const float4 rl = (jj == 0) ? r0 : (jj == 1) ? r1 : r2;
                    const float4 rh = (jj == 0) ? r5 : (jj == 1) ? r6 : r7;
                    sx += rh.x - rl.x;  sy += rh.y - rl.y;
                    sz += rh.z - rl.z;  sw += rh.w - rl.w;
                }
            }
        } else {                                // border: per-output scalar
#pragma unroll
            for (int jj = 0; jj < 4; ++jj) {
                int j2 = j4 + jj;
                int gyc = min(max(y0 - 2 + j2, 0), H - 1);
                int js  = gyc - y0 + 2;
#pragma unroll
                for (int e = 0; e < 2; ++e) {
                    int is = min(max(g0 + e, 0), W - 1) - x0 + 2;
                    float ss = 0.f, sq = 0.f;
#pragma unroll
                    for (int r = 0; r < 5; ++r) {
                        float2 v = s_su[js + r][is];
                        ss += v.x; sq += v.y;
                    }
                    float mean = ss * 0.04f, msq = sq * 0.04f;
                    float var  = fabsf(msq - mean * mean);
                    s_vw[j2][c + e].w = __expf(-var * 64.0f * s_vw[j2][c + e].w);
                }
            }
        }
    }
    __syncthreads();

    // ---- stage 4: 25-tap filter; factorized row sums shared across 4 px ----
    float accR[4], accG[4], accB[4], accW[4];
    float ctrR[4], ctrG[4], ctrB[4];
#pragma unroll
    for (int p = 0; p < 4; ++p) { accR[p] = accG[p] = accB[p] = accW[p] = 0.f; }

#pragma unroll
    for (int r = 0; r < 8; ++r) {
        const float4* row = &s_vw[pr0 + r][tx];      // single base, imm offsets
        float4 a0 = row[0], a1 = row[1], a2 = row[2], a3 = row[3], a4 = row[4];
        // partial sums by |dx|: S0 (dx=0), S1 (|dx|=1), S2 (|dx|=2)
        float S0w = a2.w;
        float S0x = a2.w * a2.x, S0y = a2.w * a2.y, S0z = a2.w * a2.z;
        float S1w = a1.w + a3.w;
        float S1x = a1.w * a1.x + a3.w * a3.x;
        float S1y = a1.w * a1.y + a3.w * a3.y;
        float S1z = a1.w * a1.z + a3.w * a3.z;
        float S2w = a0.w + a4.w;
        float S2x = a0.w * a0.x + a4.w * a4.x;
        float S2y = a0.w * a0.y + a4.w * a4.y;
        float S2z = a0.w * a0.z + a4.w * a4.z;
#pragma unroll
        for (int p = 0; p < 4; ++p) {
            const int dy = r - 2 - p;                // compile-time after unroll
            if (dy < -2 || dy > 2) continue;
            const int ady = dy < 0 ? -dy : dy;
            float rw = S0w + t1[p] * S1w + t4[p] * S2w;
            float rx = S0x + t1[p] * S1x + t4[p] * S2x;
            float ry = S0y + t1[p] * S1y + t4[p] * S2y;
            float rz = S0z + t1[p] * S1z + t4[p] * S2z;
            if (ady == 0) {                          // center row: capture rgb
                ctrR[p] = a2.x; ctrG[p] = a2.y; ctrB[p] = a2.z;
                accR[p] += rx; accG[p] += ry; accB[p] += rz; accW[p] += rw;
            } else {
                float rf = (ady == 1) ? t1[p] : t4[p];
                accR[p] += rf * rx; accG[p] += rf * ry;
                accB[p] += rf * rz; accW[p] += rf * rw;
            }
        }
    }

    float* __restrict__ oR = out + ((size_t)(3*n + 0) << 20);
    float* __restrict__ oG = out + ((size_t)(3*n + 1) << 20);
    float* __restrict__ oB = out + ((size_t)(3*n + 2) << 20);
#pragma unroll
    for (int p = 0; p < 4; ++p) {
        float cb = 16.0f + kc[p] * (0.001f - 16.0f); // center boost
        accR[p] += cb * ctrR[p];
        accG[p] += cb * ctrG[p];
        accB[p] += cb * ctrB[p];
        accW[p] += cb;
        float inv = __builtin_amdgcn_rcpf(accW[p]);
        int off = ((y0 + pr0 + p) << 10) + gx;
        oR[off] = ctrR[p] + kc[p] * (accR[p] * inv - ctrR[p]);
        oG[off] = ctrG[p] + kc[p] * (accG[p] * inv - ctrG[p]);
        oB[off] = ctrB[p] + kc[p] * (accB[p] * inv - ctrB[p]);
    }
}

extern "C" void kernel_launch(void* const* d_in, const int* in_sizes, int n_in,
                              void* d_out, int out_size, void* d_ws, size_t ws_size,
                              hipStream_t stream) {
    const float* inp = (const float*)d_in[0];
    float* out = (float*)d_out;
    hipLaunchKernelGGL(kuwahara_kernel, dim3(4096), dim3(256), 0, stream, inp, out);
}